// Round 4
// baseline (310.032 us; speedup 1.0000x reference)
//
#include <hip/hip_runtime.h>

#define EPS 1e-5f
#define SLOPE 0.2f

// Copy-free LayerNorm + LeakyReLU over N register-resident elements.
// 4 parallel reduction chains (no t[N] temp copy), LeakyReLU = max(t, 0.2t).
template<int N>
__device__ __forceinline__ void ln_lrelu(float* h, const float* __restrict__ g,
                                         const float* __restrict__ b) {
  float m, v;
  if constexpr (N >= 4) {
    float s0 = 0.f, s1 = 0.f, s2 = 0.f, s3 = 0.f;
#pragma unroll
    for (int j = 0; j < N; j += 4) {
      s0 += h[j]; s1 += h[j + 1]; s2 += h[j + 2]; s3 += h[j + 3];
    }
    m = ((s0 + s1) + (s2 + s3)) * (1.0f / N);
    float v0 = 0.f, v1 = 0.f, v2 = 0.f, v3 = 0.f;
#pragma unroll
    for (int j = 0; j < N; j += 4) {
      float d0 = h[j] - m, d1 = h[j + 1] - m, d2 = h[j + 2] - m, d3 = h[j + 3] - m;
      v0 = fmaf(d0, d0, v0); v1 = fmaf(d1, d1, v1);
      v2 = fmaf(d2, d2, v2); v3 = fmaf(d3, d3, v3);
    }
    v = ((v0 + v1) + (v2 + v3)) * (1.0f / N);
  } else {
    float s = 0.f;
#pragma unroll
    for (int j = 0; j < N; ++j) s += h[j];
    m = s * (1.0f / N);
    float vv = 0.f;
#pragma unroll
    for (int j = 0; j < N; ++j) { float d = h[j] - m; vv = fmaf(d, d, vv); }
    v = vv * (1.0f / N);
  }
  float rs = rsqrtf(v + EPS);
#pragma unroll
  for (int j = 0; j < N; ++j) {
    float t = (h[j] - m) * rs * g[j] + b[j];
    h[j] = fmaxf(t, SLOPE * t);   // LeakyReLU(0.2), exact for both signs
  }
}

template<int DIN, int DOUT>
__device__ __forceinline__ void linear(const float* hin, float* hout,
                                       const float* __restrict__ W) {
#pragma unroll
  for (int j = 0; j < DOUT; ++j) hout[j] = 0.f;
#pragma unroll
  for (int k = 0; k < DIN; ++k) {
    float hk = hin[k];
#pragma unroll
    for (int j = 0; j < DOUT; ++j) hout[j] = fmaf(hk, W[k * DOUT + j], hout[j]);
  }
}

// Consume 16 x-columns (4 float4) against W1 rows starting at W1base.
__device__ __forceinline__ void consume16(const float4* buf,
                                          const float* __restrict__ W1base,
                                          float* h1) {
#pragma unroll
  for (int q = 0; q < 4; ++q) {
#pragma unroll
    for (int kk = 0; kk < 4; ++kk) {
      float xk = (kk == 0) ? buf[q].x : (kk == 1) ? buf[q].y
               : (kk == 2) ? buf[q].z : buf[q].w;
      const float* __restrict__ wr = W1base + (q * 4 + kk) * 32;
#pragma unroll
      for (int j = 0; j < 32; ++j) h1[j] = fmaf(xk, wr[j], h1[j]);
    }
  }
}

__global__ __launch_bounds__(256, 4) void disc_fused(
    const float* __restrict__ x,
    const float* __restrict__ W1, const float* __restrict__ g1, const float* __restrict__ b1,
    const float* __restrict__ W2, const float* __restrict__ g2, const float* __restrict__ b2,
    const float* __restrict__ W3, const float* __restrict__ g3, const float* __restrict__ b3,
    const float* __restrict__ W4, const float* __restrict__ g4, const float* __restrict__ b4,
    const float* __restrict__ W5, const float* __restrict__ g5, const float* __restrict__ b5,
    const float* __restrict__ W6, const float* __restrict__ g6, const float* __restrict__ b6,
    const float* __restrict__ W7, const float* __restrict__ g7, const float* __restrict__ b7,
    const float* __restrict__ W8, const float* __restrict__ b8,
    float* __restrict__ out, int nrows) {
  const long row = (long)blockIdx.x * 256 + threadIdx.x;
  if (row >= (long)nrows) return;

  // ---- Layer 1 (128->32): direct per-thread row loads, ping-pong pipelined.
  // Burst i = 4 float4 = columns [16i,16i+16). Consume A, refill A two bursts
  // ahead while consuming B (1024 FMA-cycles cover each load's HBM latency).
  const float4* __restrict__ xr4 = reinterpret_cast<const float4*>(x) + row * 32;
  float h1[32];
#pragma unroll
  for (int j = 0; j < 32; ++j) h1[j] = 0.f;

  float4 A[4], B[4];
#pragma unroll
  for (int q = 0; q < 4; ++q) A[q] = xr4[q];
#pragma unroll
  for (int q = 0; q < 4; ++q) B[q] = xr4[4 + q];

#pragma unroll 1
  for (int bb = 0; bb < 3; ++bb) {
    consume16(A, W1 + (bb * 32) * 32, h1);          // cols 32bb..+15
#pragma unroll
    for (int q = 0; q < 4; ++q) A[q] = xr4[(2 * bb + 2) * 4 + q];
    consume16(B, W1 + (bb * 32 + 16) * 32, h1);     // cols 32bb+16..+31
#pragma unroll
    for (int q = 0; q < 4; ++q) B[q] = xr4[(2 * bb + 3) * 4 + q];
  }
  consume16(A, W1 + 96 * 32, h1);                   // cols 96..111
  consume16(B, W1 + 112 * 32, h1);                  // cols 112..127
  ln_lrelu<32>(h1, g1, b1);

  // ---- Layer 2 (32->64): h2 register-resident, single W2 pass. ----
  float h2[64];
  linear<32, 64>(h1, h2, W2);      // h1 dies here
  ln_lrelu<64>(h2, g2, b2);

  // ---- Layer 3 (64->32) ----
  float h3[32];
  linear<64, 32>(h2, h3, W3);      // h2 dies here
  ln_lrelu<32>(h3, g3, b3);

  float h4[16]; linear<32, 16>(h3, h4, W4); ln_lrelu<16>(h4, g4, b4);
  float h5[8];  linear<16, 8>(h4, h5, W5);  ln_lrelu<8>(h5, g5, b5);
  float h6[4];  linear<8, 4>(h5, h6, W6);   ln_lrelu<4>(h6, g6, b6);
  float h7[2];  linear<4, 2>(h6, h7, W7);   ln_lrelu<2>(h7, g7, b7);

  out[row] = fmaf(h7[1], W8[1], fmaf(h7[0], W8[0], b8[0]));
}

extern "C" void kernel_launch(void* const* d_in, const int* in_sizes, int n_in,
                              void* d_out, int out_size, void* d_ws, size_t ws_size,
                              hipStream_t stream) {
  const float* x  = (const float*)d_in[0];
  const float* W1 = (const float*)d_in[1];
  const float* g1 = (const float*)d_in[2];
  const float* b1 = (const float*)d_in[3];
  const float* W2 = (const float*)d_in[4];
  const float* g2 = (const float*)d_in[5];
  const float* b2 = (const float*)d_in[6];
  const float* W3 = (const float*)d_in[7];
  const float* g3 = (const float*)d_in[8];
  const float* b3 = (const float*)d_in[9];
  const float* W4 = (const float*)d_in[10];
  const float* g4 = (const float*)d_in[11];
  const float* b4 = (const float*)d_in[12];
  const float* W5 = (const float*)d_in[13];
  const float* g5 = (const float*)d_in[14];
  const float* b5 = (const float*)d_in[15];
  const float* W6 = (const float*)d_in[16];
  const float* g6 = (const float*)d_in[17];
  const float* b6 = (const float*)d_in[18];
  const float* W7 = (const float*)d_in[19];
  const float* g7 = (const float*)d_in[20];
  const float* b7 = (const float*)d_in[21];
  const float* W8 = (const float*)d_in[22];
  const float* b8 = (const float*)d_in[23];
  float* out = (float*)d_out;

  const int nrows = in_sizes[0] / 128;          // 524288
  const int grid = (nrows + 255) / 256;         // 2048
  hipLaunchKernelGGL(disc_fused, dim3(grid), dim3(256), 0, stream,
                     x, W1, g1, b1, W2, g2, b2, W3, g3, b3, W4, g4, b4,
                     W5, g5, b5, W6, g6, b6, W7, g7, b7, W8, b8, out, nrows);
}